// Round 11
// baseline (480.552 us; speedup 1.0000x reference)
//
#include <hip/hip_runtime.h>
#include <hip/hip_bf16.h>

#define EPSV 1e-5f

typedef __attribute__((ext_vector_type(8))) short short8;   // 8 bf16
typedef __attribute__((ext_vector_type(4))) short short4v;  // 4 bf16
typedef __attribute__((ext_vector_type(4))) float f32x4;

static __device__ __forceinline__ short f2bf(float f) {
    unsigned int u = __builtin_bit_cast(unsigned int, f);
    unsigned int r = (u + 0x7FFFu + ((u >> 16) & 1u)) >> 16;
    return (short)(r & 0xFFFFu);
}
static __device__ __forceinline__ f32x4 zero4() { f32x4 z = {0.f, 0.f, 0.f, 0.f}; return z; }

static __device__ __forceinline__ void gload16(const void* g, void* l) {
    __builtin_amdgcn_global_load_lds((const unsigned int*)g, (unsigned int*)l, 16, 0, 0);
}

// ---------------------------------------------------------------------------
// Prep: BN-fold weights, reformat to MFMA-fragment-major bf16 (unchanged).
// ---------------------------------------------------------------------------
__global__ void sfe_prep(
    const float* __restrict__ w1, const float* __restrict__ b1,
    const float* __restrict__ w2, const float* __restrict__ b2,
    const float* __restrict__ w3, const float* __restrict__ b3,
    const float* __restrict__ g1, const float* __restrict__ be1,
    const float* __restrict__ m1, const float* __restrict__ v1,
    const float* __restrict__ g2, const float* __restrict__ be2,
    const float* __restrict__ m2, const float* __restrict__ v2,
    const float* __restrict__ g3, const float* __restrict__ be3,
    const float* __restrict__ m3, const float* __restrict__ v3,
    short* __restrict__ W2f, short* __restrict__ W3f,
    float* __restrict__ s1o, float* __restrict__ bb1o,
    float* __restrict__ bb2o, float* __restrict__ bb3o)
{
    int idx = blockIdx.x * 256 + threadIdx.x;          // [0, 196608)
    int e = idx & 7, lane = (idx >> 3) & 63, ct = (idx >> 9) & 15;
    int lr = lane & 15, lg = lane >> 4;
    {   // W3f
        int kc = idx >> 13;                            // 0..23
        int c3 = ct * 16 + lr;
        int c2in = (kc & 7) * 32 + lg * 8 + e;
        int dk = kc >> 3;
        float s = g3[c3] / sqrtf(v3[c3] + EPSV);
        W3f[idx] = f2bf(w3[(c3 * 256 + c2in) * 3 + dk] * s);
    }
    if (idx < 98304) {   // W2f
        int kc = idx >> 13;                            // 0..11
        int c2 = ct * 16 + lr;
        int ci = (kc & 3) * 32 + lg * 8 + e;
        int dk = kc >> 2;
        float s = g2[c2] / sqrtf(v2[c2] + EPSV);
        W2f[idx] = f2bf(w2[(c2 * 128 + ci) * 3 + dk] * s);
    }
    if (idx < 128) {
        float s = g1[idx] / sqrtf(v1[idx] + EPSV);
        s1o[idx]  = s;
        bb1o[idx] = (b1[idx] - m1[idx]) * s + be1[idx];
    }
    if (idx < 256) {
        float s2 = g2[idx] / sqrtf(v2[idx] + EPSV);
        bb2o[idx] = (b2[idx] - m2[idx]) * s2 + be2[idx];
        float s3 = g3[idx] / sqrtf(v3[idx] + EPSV);
        bb3o[idx] = (b3[idx] - m3[idx]) * s3 + be3[idx];
    }
}

#define MFMA16(A, B, C) __builtin_amdgcn_mfma_f32_16x16x32_bf16(A, B, C, 0, 0, 0)

// ---------------------------------------------------------------------------
// K_A: fused layer1 (VALU) + layer2 (MFMA).
// R11: 4-tile waves. Block = 1 sequence, 256 threads (4 waves, 1 wave/SIMD,
// 512-reg budget). Each wave owns 4 ct-tiles (W2r = 192 regs) -> each B
// fragment feeds 8 MFMAs instead of 4, and only 4 waves (not 8) read each
// fragment: per-CU LDS reads HALVE. No layer1 duplication (full seq/block),
// block-rounds stay 4 (vs R8's confounded half-split). Deep R7-style read
// window: 24 reads (96 regs) in flight. kc-ascending accumulation per
// output element -> bit-identical. Reg audit: W2r 192 + window 96 + acc 32
// + consts ~36 + misc ~40 = ~396 < 512.
// ---------------------------------------------------------------------------
__global__ __launch_bounds__(256, 1) void sfe_l12(
    const float* __restrict__ x, const float* __restrict__ w1,
    const short* __restrict__ W2f,
    const float* __restrict__ s1a, const float* __restrict__ bb1a,
    const float* __restrict__ bb2a,
    char* __restrict__ h2g, int seq0)
{
    __shared__ __align__(16) char ring[32768];       // 128 rows x 256B
    __shared__ __align__(16) char obuf[2][16384];    // 2 x (32 rows x 512B)
    __shared__ float xs[528];                        // xs[i] = x[i-1], zero-pad

    const int tid = threadIdx.x, lane = tid & 63, wid = tid >> 6;   // wid 0..3
    const int lr = lane & 15, lg = lane >> 4;
    const int seq = seq0 + blockIdx.x;
    char* h2b = h2g + (size_t)blockIdx.x * 270336;

    // ---- layer1 hoists: thread owns 4 channels c4..c4+3, 2 row-slots ----
    const int c4 = (tid & 31) * 4;
    const int chw = c4 >> 3;                         // 0..15 (16B chunk in h1 row)
    float w1r[12];
    #pragma unroll
    for (int e2 = 0; e2 < 4; ++e2) {
        w1r[e2 * 3 + 0] = w1[(c4 + e2) * 3 + 0];
        w1r[e2 * 3 + 1] = w1[(c4 + e2) * 3 + 1];
        w1r[e2 * 3 + 2] = w1[(c4 + e2) * 3 + 2];
    }
    const f32x4 s1v = *reinterpret_cast<const f32x4*>(s1a + c4);
    const f32x4 b1v = *reinterpret_cast<const f32x4*>(bb1a + c4);

    // ---- W2 fragments: wave owns ct tiles wid*4 + {0..3} (192 regs) ----
    short8 W2r[48];
    #pragma unroll
    for (int kc = 0; kc < 12; ++kc) {
        #pragma unroll
        for (int p = 0; p < 4; ++p)
            W2r[kc * 4 + p] = *reinterpret_cast<const short8*>(
                W2f + ((kc * 16 + wid * 4 + p) * 64 + lane) * 8);
    }
    f32x4 bias[4];
    #pragma unroll
    for (int p = 0; p < 4; ++p)
        bias[p] = *reinterpret_cast<const f32x4*>(bb2a + (wid * 4 + p) * 16 + lg * 4);

    // ---- stage x, zero ring chunk -1 (slot 7: rows 112..127, 4KB) ----
    for (int i = tid; i < 528; i += 256) {
        int l = i - 1;
        xs[i] = (l >= 0 && l < 520) ? x[(size_t)seq * 520 + l] : 0.f;
    }
    *reinterpret_cast<f32x4*>(ring + 28672 + tid * 16) = zero4();
    __syncthreads();

    // layer1 chunk: rows 16X..16X+15 -> ring (zeros for row>=520); 2 rows/thread
    auto h1chunk = [&](int X) {
        #pragma unroll
        for (int rh = 0; rh < 2; ++rh) {
            int row = X * 16 + rh * 8 + (tid >> 5);
            int rr = row & 127;
            short4v hv;
            if (row < 520) {
                float x0 = xs[row], x1 = xs[row + 1], x2 = xs[row + 2];
                #pragma unroll
                for (int e2 = 0; e2 < 4; ++e2) {
                    float a = w1r[e2 * 3] * x0 + w1r[e2 * 3 + 1] * x1 + w1r[e2 * 3 + 2] * x2;
                    hv[e2] = f2bf(fmaxf(a * s1v[e2] + b1v[e2], 0.f));
                }
            } else {
                hv[0] = 0; hv[1] = 0; hv[2] = 0; hv[3] = 0;
            }
            *reinterpret_cast<short4v*>(
                ring + rr * 256 + ((chw ^ (row & 15)) << 4) + (c4 & 7) * 2) = hv;
        }
    };

    h1chunk(0); h1chunk(1); h1chunk(2);
    __syncthreads();

    auto epi = [&](const f32x4& A, int p, int jt, int b) {
        int c2b = (wid * 4 + p) * 16 + lg * 4;
        int ch = c2b >> 3;                             // 0..31
        short4v hv;
        #pragma unroll
        for (int r = 0; r < 4; ++r) hv[r] = f2bf(fmaxf(A[r] + bias[p][r], 0.f));
        *reinterpret_cast<short4v*>(
            obuf[b] + (jt * 16 + lr) * 512 + ((ch ^ lr) << 4) + (c2b & 7) * 2) = hv;
    };

    for (int C = 0; C <= 32; C += 2) {
        const bool do2 = (C < 32);                     // jtile C+1 valid (<=32)
        const int b = (C >> 1) & 1;
        f32x4 a0[4] = {zero4(), zero4(), zero4(), zero4()};   // jt0, p0..3
        f32x4 a1[4] = {zero4(), zero4(), zero4(), zero4()};   // jt1, p0..3
        const int row0base = C * 16 + lr - 1;

        // B-fragment read: kc (compile-time), jt = 0/1 (row +0/+16)
        auto readB = [&](int kc, int jt) -> short8 {
            int dk = kc >> 2, cc = kc & 3;
            int ch = cc * 4 + lg;                      // 0..15
            int row = row0base + dk + jt * 16;
            return *reinterpret_cast<const short8*>(
                ring + ((row + 128) & 127) * 256 + ((ch ^ (row & 15)) << 4));
        };

        if (do2) {
            short8 B0a[6], B1a[6], B0b[6], B1b[6];
            // issue G0 (kc 0..5): 12 ds_reads
            #pragma unroll
            for (int k = 0; k < 6; ++k) { B0a[k] = readB(k, 0); B1a[k] = readB(k, 1); }
            __builtin_amdgcn_sched_barrier(0);
            // issue G1 (kc 6..11): 12 more -> 24 in flight
            #pragma unroll
            for (int k = 0; k < 6; ++k) { B0b[k] = readB(k + 6, 0); B1b[k] = readB(k + 6, 1); }
            __builtin_amdgcn_sched_barrier(0);
            // consume G0 (kc ascending; 8 MFMA per fragment-pair)
            #pragma unroll
            for (int k = 0; k < 6; ++k) {
                #pragma unroll
                for (int p = 0; p < 4; ++p) {
                    a0[p] = MFMA16(W2r[k * 4 + p], B0a[k], a0[p]);
                    a1[p] = MFMA16(W2r[k * 4 + p], B1a[k], a1[p]);
                }
            }
            __builtin_amdgcn_sched_barrier(0);
            // consume G1
            #pragma unroll
            for (int k = 0; k < 6; ++k) {
                #pragma unroll
                for (int p = 0; p < 4; ++p) {
                    a0[p] = MFMA16(W2r[(k + 6) * 4 + p], B0b[k], a0[p]);
                    a1[p] = MFMA16(W2r[(k + 6) * 4 + p], B1b[k], a1[p]);
                }
            }
        } else {
            // tail jtile 32: single-jtile, 12 reads in 2 groups of 6
            short8 B0a[6], B0b[6];
            #pragma unroll
            for (int k = 0; k < 6; ++k) B0a[k] = readB(k, 0);
            __builtin_amdgcn_sched_barrier(0);
            #pragma unroll
            for (int k = 0; k < 6; ++k) B0b[k] = readB(k + 6, 0);
            __builtin_amdgcn_sched_barrier(0);
            #pragma unroll
            for (int k = 0; k < 6; ++k) {
                #pragma unroll
                for (int p = 0; p < 4; ++p)
                    a0[p] = MFMA16(W2r[k * 4 + p], B0a[k], a0[p]);
            }
            #pragma unroll
            for (int k = 0; k < 6; ++k) {
                #pragma unroll
                for (int p = 0; p < 4; ++p)
                    a0[p] = MFMA16(W2r[(k + 6) * 4 + p], B0b[k], a0[p]);
            }
        }

        // produce h1 chunks C+3, C+4 (disjoint slots from MFMA-phase reads)
        if (C + 3 <= 32) h1chunk(C + 3);
        if (C + 4 <= 32) h1chunk(C + 4);

        // D epilogue -> obuf[b]
        #pragma unroll
        for (int p = 0; p < 4; ++p) epi(a0[p], p, 0, b);
        if (do2) {
            #pragma unroll
            for (int p = 0; p < 4; ++p) epi(a1[p], p, 1, b);
        }

        // LDS-only drain: ring/obuf writes visible; h2 stores stay in flight.
        asm volatile("s_waitcnt lgkmcnt(0)" ::: "memory");
        __builtin_amdgcn_s_barrier();

        // cooperative coalesced store of rows 16C..16C+31 (zeros for rows>=520)
        #pragma unroll
        for (int q = 0; q < 4; ++q) {
            int byteo = q * 4096 + tid * 16;
            int lrow = byteo >> 9;
            int grow = C * 16 + lrow;
            if (grow < 528 && (do2 || lrow < 16)) {
                short8 d = *reinterpret_cast<const short8*>(obuf[b] + byteo);
                if (grow >= 520) { short8 z = {0,0,0,0,0,0,0,0}; d = z; }
                *reinterpret_cast<short8*>(h2b + (size_t)grow * 512 + (byteo & 511)) = d;
            }
        }
    }
}

// ---------------------------------------------------------------------------
// K_B: layer3 (MFMA) + mean pool. (R10 kernel, verified 265us — frozen.)
// Block = 256 threads (4 waves, 1/SIMD, 512-reg budget), 8-ct-tile half per
// block, 2 blocks/seq. Super-iteration: 4 jtiles per barrier, 12-slot ring
// (96KB), hoisted Koff addressing, 32 reads in flight, counted vmcnt.
// ---------------------------------------------------------------------------
__global__ __launch_bounds__(256, 1) void sfe_l3(
    const char* __restrict__ h2g, const short* __restrict__ W3f,
    const float* __restrict__ bb3a, float* __restrict__ out, int seq0)
{
    __shared__ __align__(16) char ring[98304];       // 12 slots x 8KB (16 rows x 512B)

    const int tid = threadIdx.x, lane = tid & 63, wid = tid >> 6;   // wid 0..3
    const int lr = lane & 15, lg = lane >> 4;
    const int bi = blockIdx.x;
    const int seq = seq0 + (bi >> 1);
    const int ch2 = bi & 1;                          // ct half: tiles ch2*8..ch2*8+7
    const char* h2b = h2g + (size_t)(bi >> 1) * 270336;

    // ---- W3 fragments: wave owns ct tiles ch2*8 + wid*2 + {0,1} (192 regs) ----
    short8 W3r[48];
    #pragma unroll
    for (int kc = 0; kc < 24; ++kc) {
        #pragma unroll
        for (int p = 0; p < 2; ++p)
            W3r[kc * 2 + p] = *reinterpret_cast<const short8*>(
                W3f + ((kc * 16 + ch2 * 8 + wid * 2 + p) * 64 + lane) * 8);
    }
    const f32x4 bias0 = *reinterpret_cast<const f32x4*>(bb3a + (ch2 * 8 + wid * 2 + 0) * 16 + lg * 4);
    const f32x4 bias1 = *reinterpret_cast<const f32x4*>(bb3a + (ch2 * 8 + wid * 2 + 1) * 16 + lg * 4);
    f32x4 pool0 = zero4(), pool1 = zero4();

    // ---- iter/jt-invariant byte offsets: Koff[kc] = (ch ^ ((lr-1+dk)&15))<<4
    int Koff[24];
    #pragma unroll
    for (int kc = 0; kc < 24; ++kc) {
        int dk = kc >> 3, cc = kc & 7;
        Koff[kc] = (((cc * 4 + lg) ^ ((lr - 1 + dk) & 15)) << 4);
    }

    auto stage = [&](int X) {          // stage h2 rows 16X..16X+15 (8KB, 2 instrs)
        int Xc = X > 32 ? 32 : X;      // clamp source: in-seq; garbage slots
                                       // are unread or pool-masked
        int slot = X % 12;
        #pragma unroll
        for (int q = 0; q < 2; ++q)
            gload16(h2b + Xc * 8192 + q * 4096 + tid * 16,
                    ring + slot * 8192 + q * 4096 + tid * 16);
    };

    // zero slot 11 (chunk -1, 8KB), stage chunks 0..6
    #pragma unroll
    for (int q = 0; q < 2; ++q)
        *reinterpret_cast<f32x4*>(ring + 90112 + q * 4096 + tid * 16) = zero4();
    stage(0); stage(1); stage(2); stage(3); stage(4); stage(5); stage(6);
    // chunks 0..4 landed (S=0 reads -1..4); 5,6 (4 instrs) stay in flight
    asm volatile("s_waitcnt vmcnt(4) lgkmcnt(0)" ::: "memory");
    __builtin_amdgcn_s_barrier();

    // read helper (KCB+k, jt compile-time after unroll): 1 add per read
    #define RD(rbarr, KC, JT) \
        (*reinterpret_cast<const short8*>(ring + rbarr[(JT) * 3 + ((KC) >> 3)] + Koff[(KC)]))

    for (int S = 0; S <= 28; S += 4) {
        // issue next prefetches first; they ride across the whole iter + barrier
        stage(S + 7); stage(S + 8); stage(S + 9); stage(S + 10);
        __builtin_amdgcn_sched_barrier(0);

        // 12 row-bases for this super-iter: slot-row byte base for (jt, dk)
        int rb[12];
        #pragma unroll
        for (int jt = 0; jt < 4; ++jt) {
            #pragma unroll
            for (int dk = 0; dk < 3; ++dk)
                rb[jt * 3 + dk] = (((S + jt) * 16 + lr - 1 + dk + 192) % 192) * 512;
        }

        f32x4 a0[4] = {zero4(), zero4(), zero4(), zero4()};
        f32x4 a1[4] = {zero4(), zero4(), zero4(), zero4()};
        short8 Ba[16], Bb[16];

        #define ISSUE(BUF, KCB) \
            _Pragma("unroll") for (int k = 0; k < 4; ++k) { \
                _Pragma("unroll") for (int jt = 0; jt < 4; ++jt) \
                    BUF[k * 4 + jt] = RD(rb, (KCB) + k, jt); \
            } \
            __builtin_amdgcn_sched_barrier(0);

        #define CONSUME(BUF, KCB) \
            _Pragma("unroll") for (int k = 0; k < 4; ++k) { \
                _Pragma("unroll") for (int jt = 0; jt < 4; ++jt) { \
                    a0[jt] = MFMA16(W3r[((KCB) + k) * 2 + 0], BUF[k * 4 + jt], a0[jt]); \
                    a1[jt] = MFMA16(W3r[((KCB) + k) * 2 + 1], BUF[k * 4 + jt], a1[jt]); \
                } \
            } \
            __builtin_amdgcn_sched_barrier(0);

        ISSUE(Ba, 0)            // 16 reads in flight
        ISSUE(Bb, 4)            // 32 in flight
        CONSUME(Ba, 0)
        ISSUE(Ba, 8)
        CONSUME(Bb, 4)
        ISSUE(Bb, 12)
        CONSUME(Ba, 8)
        ISSUE(Ba, 16)
        CONSUME(Bb, 12)
        ISSUE(Bb, 20)
        CONSUME(Ba, 16)
        CONSUME(Bb, 20)

        #undef ISSUE
        #undef CONSUME

        // pool: jtiles S..S+3 <= 31 -> all columns valid, no masking
        #pragma unroll
        for (int jt = 0; jt < 4; ++jt) {
            f32x4 t0, t1;
            #pragma unroll
            for (int r = 0; r < 4; ++r) {
                t0[r] = fmaxf(a0[jt][r] + bias0[r], 0.f);
                t1[r] = fmaxf(a1[jt][r] + bias1[r], 0.f);
            }
            pool0 += t0;
            pool1 += t1;
        }

        // counted drain: landed through S+8; S+9,S+10 (4 instrs) in flight.
        // lgkmcnt(0): no ds_read straddles next iter's DMA overwrites.
        asm volatile("s_waitcnt vmcnt(4) lgkmcnt(0)" ::: "memory");
        __builtin_amdgcn_s_barrier();
    }

    // ---- tail: jtile 32 (reads chunks 31,32,33 -> slots 7,8,9, all landed) ----
    {
        int rbT[3];
        #pragma unroll
        for (int dk = 0; dk < 3; ++dk)
            rbT[dk] = ((512 + lr - 1 + dk + 192) % 192) * 512;

        f32x4 a00 = zero4(), a10 = zero4();
        short8 Ta[12], Tb[12];
        #pragma unroll
        for (int k = 0; k < 12; ++k)
            Ta[k] = *reinterpret_cast<const short8*>(ring + rbT[k >> 3] + Koff[k]);
        __builtin_amdgcn_sched_barrier(0);
        #pragma unroll
        for (int k = 0; k < 12; ++k)
            Tb[k] = *reinterpret_cast<const short8*>(ring + rbT[(k + 12) >> 3] + Koff[k + 12]);
        __builtin_amdgcn_sched_barrier(0);
        #pragma unroll
        for (int k = 0; k < 12; ++k) {
            a00 = MFMA16(W3r[k * 2 + 0], Ta[k], a00);
            a10 = MFMA16(W3r[k * 2 + 1], Ta[k], a10);
        }
        #pragma unroll
        for (int k = 0; k < 12; ++k) {
            a00 = MFMA16(W3r[(k + 12) * 2 + 0], Tb[k], a00);
            a10 = MFMA16(W3r[(k + 12) * 2 + 1], Tb[k], a10);
        }

        bool v0 = (512 + lr) < 520;
        f32x4 t0, t1;
        #pragma unroll
        for (int r = 0; r < 4; ++r) {
            t0[r] = fmaxf(a00[r] + bias0[r], 0.f);
            t1[r] = fmaxf(a10[r] + bias1[r], 0.f);
        }
        pool0 += v0 ? t0 : zero4();
        pool1 += v0 ? t1 : zero4();
    }

    // drain leftover prefetches before LDS goes out of scope
    asm volatile("s_waitcnt vmcnt(0)" ::: "memory");

    // reduce over the 16 lr lanes, write out (this block's 128-ch half)
    #pragma unroll
    for (int d = 1; d < 16; d <<= 1) {
        #pragma unroll
        for (int r = 0; r < 4; ++r) {
            pool0[r] += __shfl_xor(pool0[r], d, 64);
            pool1[r] += __shfl_xor(pool1[r], d, 64);
        }
    }
    if (lr == 0) {
        f32x4 o0, o1;
        #pragma unroll
        for (int r = 0; r < 4; ++r) { o0[r] = pool0[r] * (1.f / 520.f); o1[r] = pool1[r] * (1.f / 520.f); }
        *reinterpret_cast<f32x4*>(out + (size_t)seq * 256 + (ch2 * 8 + wid * 2 + 0) * 16 + lg * 4) = o0;
        *reinterpret_cast<f32x4*>(out + (size_t)seq * 256 + (ch2 * 8 + wid * 2 + 1) * 16 + lg * 4) = o1;
    }
}

// ---------------------------------------------------------------------------
extern "C" void kernel_launch(void* const* d_in, const int* in_sizes, int n_in,
                              void* d_out, int out_size, void* d_ws, size_t ws_size,
                              hipStream_t stream) {
    (void)n_in; (void)out_size;
    const float* x   = (const float*)d_in[0];
    const float* w1  = (const float*)d_in[1];
    const float* b1  = (const float*)d_in[2];
    const float* w2  = (const float*)d_in[3];
    const float* b2  = (const float*)d_in[4];
    const float* w3  = (const float*)d_in[5];
    const float* b3  = (const float*)d_in[6];
    const float* g1  = (const float*)d_in[7];
    const float* be1 = (const float*)d_in[8];
    const float* m1  = (const float*)d_in[9];
    const float* v1  = (const float*)d_in[10];
    const float* g2  = (const float*)d_in[11];
    const float* be2 = (const float*)d_in[12];
    const float* m2  = (const float*)d_in[13];
    const float* v2  = (const float*)d_in[14];
    const float* g3  = (const float*)d_in[15];
    const float* be3 = (const float*)d_in[16];
    const float* m3  = (const float*)d_in[17];
    const float* v3  = (const float*)d_in[18];

    char* ws = (char*)d_ws;
    short* W2f  = (short*)(ws);               // 98304  bf16 = 196608 B
    short* W3f  = (short*)(ws + 196608);      // 196608 bf16 = 393216 B
    float* s1o  = (float*)(ws + 589824);
    float* bb1o = (float*)(ws + 590336);
    float* bb2o = (float*)(ws + 590848);
    float* bb3o = (float*)(ws + 591872);
    char*  h2g  = ws + (1 << 20);             // h2 staging: 270336 B / seq

    int nseq = in_sizes[0] / 520;             // 1024
    size_t h2cap = ws_size > (size_t)(1 << 20) ? ws_size - (1 << 20) : 0;
    int maxseq = (int)(h2cap / 270336);
    if (maxseq < 1) maxseq = 1;
    if (maxseq > nseq) maxseq = nseq;

    sfe_prep<<<768, 256, 0, stream>>>(w1, b1, w2, b2, w3, b3,
                                      g1, be1, m1, v1, g2, be2, m2, v2,
                                      g3, be3, m3, v3,
                                      W2f, W3f, s1o, bb1o, bb2o, bb3o);
    for (int s0 = 0; s0 < nseq; s0 += maxseq) {
        int n = (nseq - s0) < maxseq ? (nseq - s0) : maxseq;
        sfe_l12<<<n, 256, 0, stream>>>(x, w1, W2f, s1o, bb1o, bb2o, h2g, s0);
        sfe_l3 <<<n * 2, 256, 0, stream>>>(h2g, W3f, bb3o, (float*)d_out, s0);
    }
}

// Round 12
// 426.872 us; speedup vs baseline: 1.1258x; 1.1258x over previous
//
#include <hip/hip_runtime.h>
#include <hip/hip_bf16.h>

#define EPSV 1e-5f

typedef __attribute__((ext_vector_type(8))) short short8;   // 8 bf16
typedef __attribute__((ext_vector_type(4))) short short4v;  // 4 bf16
typedef __attribute__((ext_vector_type(4))) float f32x4;

static __device__ __forceinline__ short f2bf(float f) {
    unsigned int u = __builtin_bit_cast(unsigned int, f);
    unsigned int r = (u + 0x7FFFu + ((u >> 16) & 1u)) >> 16;
    return (short)(r & 0xFFFFu);
}
static __device__ __forceinline__ f32x4 zero4() { f32x4 z = {0.f, 0.f, 0.f, 0.f}; return z; }

static __device__ __forceinline__ void gload16(const void* g, void* l) {
    __builtin_amdgcn_global_load_lds((const unsigned int*)g, (unsigned int*)l, 16, 0, 0);
}

// ---------------------------------------------------------------------------
// Prep: BN-fold weights, reformat to MFMA-fragment-major bf16 (unchanged).
// ---------------------------------------------------------------------------
__global__ void sfe_prep(
    const float* __restrict__ w1, const float* __restrict__ b1,
    const float* __restrict__ w2, const float* __restrict__ b2,
    const float* __restrict__ w3, const float* __restrict__ b3,
    const float* __restrict__ g1, const float* __restrict__ be1,
    const float* __restrict__ m1, const float* __restrict__ v1,
    const float* __restrict__ g2, const float* __restrict__ be2,
    const float* __restrict__ m2, const float* __restrict__ v2,
    const float* __restrict__ g3, const float* __restrict__ be3,
    const float* __restrict__ m3, const float* __restrict__ v3,
    short* __restrict__ W2f, short* __restrict__ W3f,
    float* __restrict__ s1o, float* __restrict__ bb1o,
    float* __restrict__ bb2o, float* __restrict__ bb3o)
{
    int idx = blockIdx.x * 256 + threadIdx.x;          // [0, 196608)
    int e = idx & 7, lane = (idx >> 3) & 63, ct = (idx >> 9) & 15;
    int lr = lane & 15, lg = lane >> 4;
    {   // W3f
        int kc = idx >> 13;                            // 0..23
        int c3 = ct * 16 + lr;
        int c2in = (kc & 7) * 32 + lg * 8 + e;
        int dk = kc >> 3;
        float s = g3[c3] / sqrtf(v3[c3] + EPSV);
        W3f[idx] = f2bf(w3[(c3 * 256 + c2in) * 3 + dk] * s);
    }
    if (idx < 98304) {   // W2f
        int kc = idx >> 13;                            // 0..11
        int c2 = ct * 16 + lr;
        int ci = (kc & 3) * 32 + lg * 8 + e;
        int dk = kc >> 2;
        float s = g2[c2] / sqrtf(v2[c2] + EPSV);
        W2f[idx] = f2bf(w2[(c2 * 128 + ci) * 3 + dk] * s);
    }
    if (idx < 128) {
        float s = g1[idx] / sqrtf(v1[idx] + EPSV);
        s1o[idx]  = s;
        bb1o[idx] = (b1[idx] - m1[idx]) * s + be1[idx];
    }
    if (idx < 256) {
        float s2 = g2[idx] / sqrtf(v2[idx] + EPSV);
        bb2o[idx] = (b2[idx] - m2[idx]) * s2 + be2[idx];
        float s3 = g3[idx] / sqrtf(v3[idx] + EPSV);
        bb3o[idx] = (b3[idx] - m3[idx]) * s3 + be3[idx];
    }
}

#define MFMA16(A, B, C) __builtin_amdgcn_mfma_f32_16x16x32_bf16(A, B, C, 0, 0, 0)

// ---------------------------------------------------------------------------
// K_A: fused layer1 (VALU) + layer2 (MFMA). Block = 1 sequence, 512 threads.
// EXACT R7/R1 kernel (155us verified). 8 waves/CU keeps h1/epi/store phases
// overlapped across waves; R5/R8/R9/R11 all proved geometry/window changes
// here regress or are neutral. Do not restructure.
// ---------------------------------------------------------------------------
__global__ __launch_bounds__(512, 1) void sfe_l12(
    const float* __restrict__ x, const float* __restrict__ w1,
    const short* __restrict__ W2f,
    const float* __restrict__ s1a, const float* __restrict__ bb1a,
    const float* __restrict__ bb2a,
    char* __restrict__ h2g, int seq0)
{
    __shared__ __align__(16) char ring[32768];       // 128 rows x 256B
    __shared__ __align__(16) char obuf[2][16384];    // 2 x (32 rows x 512B)
    __shared__ float xs[528];                        // xs[i] = x[i-1], zero-pad

    const int tid = threadIdx.x, lane = tid & 63, wid = tid >> 6;
    const int lr = lane & 15, lg = lane >> 4;
    const int seq = seq0 + blockIdx.x;
    char* h2b = h2g + (size_t)blockIdx.x * 270336;

    // ---- layer1 hoists: thread owns 4 channels c4..c4+3 ----
    const int c4 = (tid & 31) * 4;
    float w1r[12];
    #pragma unroll
    for (int e2 = 0; e2 < 4; ++e2) {
        w1r[e2 * 3 + 0] = w1[(c4 + e2) * 3 + 0];
        w1r[e2 * 3 + 1] = w1[(c4 + e2) * 3 + 1];
        w1r[e2 * 3 + 2] = w1[(c4 + e2) * 3 + 2];
    }
    const f32x4 s1v = *reinterpret_cast<const f32x4*>(s1a + c4);
    const f32x4 b1v = *reinterpret_cast<const f32x4*>(bb1a + c4);

    // ---- W2 fragments: wave owns ct = 2*wid, 2*wid+1 ----
    short8 W2r[24];
    #pragma unroll
    for (int kc = 0; kc < 12; ++kc) {
        #pragma unroll
        for (int p = 0; p < 2; ++p)
            W2r[kc * 2 + p] = *reinterpret_cast<const short8*>(
                W2f + ((kc * 16 + wid * 2 + p) * 64 + lane) * 8);
    }
    const f32x4 bias0 = *reinterpret_cast<const f32x4*>(bb2a + (wid * 2 + 0) * 16 + lg * 4);
    const f32x4 bias1 = *reinterpret_cast<const f32x4*>(bb2a + (wid * 2 + 1) * 16 + lg * 4);

    // ---- stage x, zero ring chunk -1 (ringrows 112..127) ----
    for (int i = tid; i < 528; i += 512) {
        int l = i - 1;
        xs[i] = (l >= 0 && l < 520) ? x[(size_t)seq * 520 + l] : 0.f;
    }
    *reinterpret_cast<long long*>(ring + 28672 + tid * 8) = 0ll;
    __syncthreads();

    // layer1 chunk compute: rows 16X..16X+15 -> ring (zero for row>=520)
    auto h1chunk = [&](int X) {
        int row = X * 16 + (tid >> 5);
        int rr = (row + 128) & 127;
        short4v hv;
        if (row < 520) {
            float x0 = xs[row], x1 = xs[row + 1], x2 = xs[row + 2];
            #pragma unroll
            for (int e2 = 0; e2 < 4; ++e2) {
                float a = w1r[e2 * 3] * x0 + w1r[e2 * 3 + 1] * x1 + w1r[e2 * 3 + 2] * x2;
                hv[e2] = f2bf(fmaxf(a * s1v[e2] + b1v[e2], 0.f));
            }
        } else {
            hv[0] = 0; hv[1] = 0; hv[2] = 0; hv[3] = 0;
        }
        int ch = c4 >> 3;                              // 0..15
        *reinterpret_cast<short4v*>(
            ring + rr * 256 + ((ch ^ (row & 15)) << 4) + (c4 & 7) * 2) = hv;
    };

    h1chunk(0); h1chunk(1); h1chunk(2);
    __syncthreads();

    auto epi = [&](const f32x4& A, int p, const f32x4& bv, int jt, int b) {
        int c2b = (wid * 2 + p) * 16 + lg * 4;
        int ch = c2b >> 3;                             // 0..31
        short4v hv;
        #pragma unroll
        for (int r = 0; r < 4; ++r) hv[r] = f2bf(fmaxf(A[r] + bv[r], 0.f));
        *reinterpret_cast<short4v*>(
            obuf[b] + (jt * 16 + lr) * 512 + ((ch ^ lr) << 4) + (c2b & 7) * 2) = hv;
    };

    for (int C = 0; C <= 32; C += 2) {
        const bool do2 = (C < 32);                     // jtile C+1 valid (<=32)
        const int b = (C >> 1) & 1;
        f32x4 a00 = zero4(), a10 = zero4(), a01 = zero4(), a11 = zero4();
        const int row0base = C * 16 + lr - 1;

        if (do2) {
            #pragma unroll
            for (int kc = 0; kc < 12; ++kc) {
                int dk = kc >> 2, cc = kc & 3;
                int ch = cc * 4 + lg;
                int row0 = row0base + dk, row1 = row0 + 16;
                short8 B0 = *reinterpret_cast<const short8*>(
                    ring + ((row0 + 128) & 127) * 256 + ((ch ^ (row0 & 15)) << 4));
                short8 B1 = *reinterpret_cast<const short8*>(
                    ring + ((row1 + 128) & 127) * 256 + ((ch ^ (row1 & 15)) << 4));
                a00 = MFMA16(W2r[kc * 2 + 0], B0, a00);
                a10 = MFMA16(W2r[kc * 2 + 1], B0, a10);
                a01 = MFMA16(W2r[kc * 2 + 0], B1, a01);
                a11 = MFMA16(W2r[kc * 2 + 1], B1, a11);
            }
        } else {
            #pragma unroll
            for (int kc = 0; kc < 12; ++kc) {
                int dk = kc >> 2, cc = kc & 3;
                int ch = cc * 4 + lg;
                int row0 = row0base + dk;
                short8 B0 = *reinterpret_cast<const short8*>(
                    ring + ((row0 + 128) & 127) * 256 + ((ch ^ (row0 & 15)) << 4));
                a00 = MFMA16(W2r[kc * 2 + 0], B0, a00);
                a10 = MFMA16(W2r[kc * 2 + 1], B0, a10);
            }
        }

        // produce h1 chunks C+3, C+4 (overlaps MFMA-phase LDS reads; disjoint slots)
        if (C + 3 <= 32) h1chunk(C + 3);
        if (C + 4 <= 32) h1chunk(C + 4);

        // D epilogue -> outbuf[b]
        epi(a00, 0, bias0, 0, b);
        epi(a10, 1, bias1, 0, b);
        if (do2) { epi(a01, 0, bias0, 1, b); epi(a11, 1, bias1, 1, b); }

        // LDS-only drain: ring/obuf writes visible; h2 stores stay in flight.
        asm volatile("s_waitcnt lgkmcnt(0)" ::: "memory");
        __builtin_amdgcn_s_barrier();

        // cooperative coalesced store of rows 16C..16C+31 (zeros for rows>=520)
        #pragma unroll
        for (int q = 0; q < 2; ++q) {
            int byteo = q * 8192 + tid * 16;
            int lrow = byteo >> 9;
            int grow = C * 16 + lrow;
            if (grow < 528 && (do2 || lrow < 16)) {
                short8 d = *reinterpret_cast<const short8*>(obuf[b] + byteo);
                if (grow >= 520) { short8 z = {0,0,0,0,0,0,0,0}; d = z; }
                *reinterpret_cast<short8*>(h2b + (size_t)grow * 512 + (byteo & 511)) = d;
            }
        }
    }
}

// ---------------------------------------------------------------------------
// K_B: layer3 (MFMA) + mean pool. EXACT R10 kernel (265us verified).
// Block = 256 threads (4 waves, 1/SIMD, 512-reg budget), 8-ct-tile half per
// block, 2 blocks/seq. Super-iteration: 4 jtiles per barrier, 12-slot ring
// (96KB), hoisted Koff addressing, 32 reads in flight, counted vmcnt.
// ---------------------------------------------------------------------------
__global__ __launch_bounds__(256, 1) void sfe_l3(
    const char* __restrict__ h2g, const short* __restrict__ W3f,
    const float* __restrict__ bb3a, float* __restrict__ out, int seq0)
{
    __shared__ __align__(16) char ring[98304];       // 12 slots x 8KB (16 rows x 512B)

    const int tid = threadIdx.x, lane = tid & 63, wid = tid >> 6;   // wid 0..3
    const int lr = lane & 15, lg = lane >> 4;
    const int bi = blockIdx.x;
    const int seq = seq0 + (bi >> 1);
    const int ch2 = bi & 1;                          // ct half: tiles ch2*8..ch2*8+7
    const char* h2b = h2g + (size_t)(bi >> 1) * 270336;

    // ---- W3 fragments: wave owns ct tiles ch2*8 + wid*2 + {0,1} (192 regs) ----
    short8 W3r[48];
    #pragma unroll
    for (int kc = 0; kc < 24; ++kc) {
        #pragma unroll
        for (int p = 0; p < 2; ++p)
            W3r[kc * 2 + p] = *reinterpret_cast<const short8*>(
                W3f + ((kc * 16 + ch2 * 8 + wid * 2 + p) * 64 + lane) * 8);
    }
    const f32x4 bias0 = *reinterpret_cast<const f32x4*>(bb3a + (ch2 * 8 + wid * 2 + 0) * 16 + lg * 4);
    const f32x4 bias1 = *reinterpret_cast<const f32x4*>(bb3a + (ch2 * 8 + wid * 2 + 1) * 16 + lg * 4);
    f32x4 pool0 = zero4(), pool1 = zero4();

    // ---- iter/jt-invariant byte offsets: Koff[kc] = (ch ^ ((lr-1+dk)&15))<<4
    int Koff[24];
    #pragma unroll
    for (int kc = 0; kc < 24; ++kc) {
        int dk = kc >> 3, cc = kc & 7;
        Koff[kc] = (((cc * 4 + lg) ^ ((lr - 1 + dk) & 15)) << 4);
    }

    auto stage = [&](int X) {          // stage h2 rows 16X..16X+15 (8KB, 2 instrs)
        int Xc = X > 32 ? 32 : X;      // clamp source: in-seq; garbage slots
                                       // are unread or pool-masked
        int slot = X % 12;
        #pragma unroll
        for (int q = 0; q < 2; ++q)
            gload16(h2b + Xc * 8192 + q * 4096 + tid * 16,
                    ring + slot * 8192 + q * 4096 + tid * 16);
    };

    // zero slot 11 (chunk -1, 8KB), stage chunks 0..6
    #pragma unroll
    for (int q = 0; q < 2; ++q)
        *reinterpret_cast<f32x4*>(ring + 90112 + q * 4096 + tid * 16) = zero4();
    stage(0); stage(1); stage(2); stage(3); stage(4); stage(5); stage(6);
    // chunks 0..4 landed (S=0 reads -1..4); 5,6 (4 instrs) stay in flight
    asm volatile("s_waitcnt vmcnt(4) lgkmcnt(0)" ::: "memory");
    __builtin_amdgcn_s_barrier();

    // read helper (KCB+k, jt compile-time after unroll): 1 add per read
    #define RD(rbarr, KC, JT) \
        (*reinterpret_cast<const short8*>(ring + rbarr[(JT) * 3 + ((KC) >> 3)] + Koff[(KC)]))

    for (int S = 0; S <= 28; S += 4) {
        // issue next prefetches first; they ride across the whole iter + barrier
        stage(S + 7); stage(S + 8); stage(S + 9); stage(S + 10);
        __builtin_amdgcn_sched_barrier(0);

        // 12 row-bases for this super-iter: slot-row byte base for (jt, dk)
        int rb[12];
        #pragma unroll
        for (int jt = 0; jt < 4; ++jt) {
            #pragma unroll
            for (int dk = 0; dk < 3; ++dk)
                rb[jt * 3 + dk] = (((S + jt) * 16 + lr - 1 + dk + 192) % 192) * 512;
        }

        f32x4 a0[4] = {zero4(), zero4(), zero4(), zero4()};
        f32x4 a1[4] = {zero4(), zero4(), zero4(), zero4()};
        short8 Ba[16], Bb[16];

        #define ISSUE(BUF, KCB) \
            _Pragma("unroll") for (int k = 0; k < 4; ++k) { \
                _Pragma("unroll") for (int jt = 0; jt < 4; ++jt) \
                    BUF[k * 4 + jt] = RD(rb, (KCB) + k, jt); \
            } \
            __builtin_amdgcn_sched_barrier(0);

        #define CONSUME(BUF, KCB) \
            _Pragma("unroll") for (int k = 0; k < 4; ++k) { \
                _Pragma("unroll") for (int jt = 0; jt < 4; ++jt) { \
                    a0[jt] = MFMA16(W3r[((KCB) + k) * 2 + 0], BUF[k * 4 + jt], a0[jt]); \
                    a1[jt] = MFMA16(W3r[((KCB) + k) * 2 + 1], BUF[k * 4 + jt], a1[jt]); \
                } \
            } \
            __builtin_amdgcn_sched_barrier(0);

        ISSUE(Ba, 0)            // 16 reads in flight
        ISSUE(Bb, 4)            // 32 in flight
        CONSUME(Ba, 0)
        ISSUE(Ba, 8)
        CONSUME(Bb, 4)
        ISSUE(Bb, 12)
        CONSUME(Ba, 8)
        ISSUE(Ba, 16)
        CONSUME(Bb, 12)
        ISSUE(Bb, 20)
        CONSUME(Ba, 16)
        CONSUME(Bb, 20)

        #undef ISSUE
        #undef CONSUME

        // pool: jtiles S..S+3 <= 31 -> all columns valid, no masking
        #pragma unroll
        for (int jt = 0; jt < 4; ++jt) {
            f32x4 t0, t1;
            #pragma unroll
            for (int r = 0; r < 4; ++r) {
                t0[r] = fmaxf(a0[jt][r] + bias0[r], 0.f);
                t1[r] = fmaxf(a1[jt][r] + bias1[r], 0.f);
            }
            pool0 += t0;
            pool1 += t1;
        }

        // counted drain: landed through S+8; S+9,S+10 (4 instrs) in flight.
        // lgkmcnt(0): no ds_read straddles next iter's DMA overwrites.
        asm volatile("s_waitcnt vmcnt(4) lgkmcnt(0)" ::: "memory");
        __builtin_amdgcn_s_barrier();
    }

    // ---- tail: jtile 32 (reads chunks 31,32,33 -> slots 7,8,9, all landed) ----
    {
        int rbT[3];
        #pragma unroll
        for (int dk = 0; dk < 3; ++dk)
            rbT[dk] = ((512 + lr - 1 + dk + 192) % 192) * 512;

        f32x4 a00 = zero4(), a10 = zero4();
        short8 Ta[12], Tb[12];
        #pragma unroll
        for (int k = 0; k < 12; ++k)
            Ta[k] = *reinterpret_cast<const short8*>(ring + rbT[k >> 3] + Koff[k]);
        __builtin_amdgcn_sched_barrier(0);
        #pragma unroll
        for (int k = 0; k < 12; ++k)
            Tb[k] = *reinterpret_cast<const short8*>(ring + rbT[(k + 12) >> 3] + Koff[k + 12]);
        __builtin_amdgcn_sched_barrier(0);
        #pragma unroll
        for (int k = 0; k < 12; ++k) {
            a00 = MFMA16(W3r[k * 2 + 0], Ta[k], a00);
            a10 = MFMA16(W3r[k * 2 + 1], Ta[k], a10);
        }
        #pragma unroll
        for (int k = 0; k < 12; ++k) {
            a00 = MFMA16(W3r[(k + 12) * 2 + 0], Tb[k], a00);
            a10 = MFMA16(W3r[(k + 12) * 2 + 1], Tb[k], a10);
        }

        bool v0 = (512 + lr) < 520;
        f32x4 t0, t1;
        #pragma unroll
        for (int r = 0; r < 4; ++r) {
            t0[r] = fmaxf(a00[r] + bias0[r], 0.f);
            t1[r] = fmaxf(a10[r] + bias1[r], 0.f);
        }
        pool0 += v0 ? t0 : zero4();
        pool1 += v0 ? t1 : zero4();
    }

    // drain leftover prefetches before LDS goes out of scope
    asm volatile("s_waitcnt vmcnt(0)" ::: "memory");

    // reduce over the 16 lr lanes, write out (this block's 128-ch half)
    #pragma unroll
    for (int d = 1; d < 16; d <<= 1) {
        #pragma unroll
        for (int r = 0; r < 4; ++r) {
            pool0[r] += __shfl_xor(pool0[r], d, 64);
            pool1[r] += __shfl_xor(pool1[r], d, 64);
        }
    }
    if (lr == 0) {
        f32x4 o0, o1;
        #pragma unroll
        for (int r = 0; r < 4; ++r) { o0[r] = pool0[r] * (1.f / 520.f); o1[r] = pool1[r] * (1.f / 520.f); }
        *reinterpret_cast<f32x4*>(out + (size_t)seq * 256 + (ch2 * 8 + wid * 2 + 0) * 16 + lg * 4) = o0;
        *reinterpret_cast<f32x4*>(out + (size_t)seq * 256 + (ch2 * 8 + wid * 2 + 1) * 16 + lg * 4) = o1;
    }
}

// ---------------------------------------------------------------------------
extern "C" void kernel_launch(void* const* d_in, const int* in_sizes, int n_in,
                              void* d_out, int out_size, void* d_ws, size_t ws_size,
                              hipStream_t stream) {
    (void)n_in; (void)out_size;
    const float* x   = (const float*)d_in[0];
    const float* w1  = (const float*)d_in[1];
    const float* b1  = (const float*)d_in[2];
    const float* w2  = (const float*)d_in[3];
    const float* b2  = (const float*)d_in[4];
    const float* w3  = (const float*)d_in[5];
    const float* b3  = (const float*)d_in[6];
    const float* g1  = (const float*)d_in[7];
    const float* be1 = (const float*)d_in[8];
    const float* m1  = (const float*)d_in[9];
    const float* v1  = (const float*)d_in[10];
    const float* g2  = (const float*)d_in[11];
    const float* be2 = (const float*)d_in[12];
    const float* m2  = (const float*)d_in[13];
    const float* v2  = (const float*)d_in[14];
    const float* g3  = (const float*)d_in[15];
    const float* be3 = (const float*)d_in[16];
    const float* m3  = (const float*)d_in[17];
    const float* v3  = (const float*)d_in[18];

    char* ws = (char*)d_ws;
    short* W2f  = (short*)(ws);               // 98304  bf16 = 196608 B
    short* W3f  = (short*)(ws + 196608);      // 196608 bf16 = 393216 B
    float* s1o  = (float*)(ws + 589824);
    float* bb1o = (float*)(ws + 590336);
    float* bb2o = (float*)(ws + 590848);
    float* bb3o = (float*)(ws + 591872);
    char*  h2g  = ws + (1 << 20);             // h2 staging: 270336 B / seq

    int nseq = in_sizes[0] / 520;             // 1024
    size_t h2cap = ws_size > (size_t)(1 << 20) ? ws_size - (1 << 20) : 0;
    int maxseq = (int)(h2cap / 270336);
    if (maxseq < 1) maxseq = 1;
    if (maxseq > nseq) maxseq = nseq;

    sfe_prep<<<768, 256, 0, stream>>>(w1, b1, w2, b2, w3, b3,
                                      g1, be1, m1, v1, g2, be2, m2, v2,
                                      g3, be3, m3, v3,
                                      W2f, W3f, s1o, bb1o, bb2o, bb3o);
    for (int s0 = 0; s0 < nseq; s0 += maxseq) {
        int n = (nseq - s0) < maxseq ? (nseq - s0) : maxseq;
        sfe_l12<<<n, 512, 0, stream>>>(x, w1, W2f, s1o, bb1o, bb2o, h2g, s0);
        sfe_l3 <<<n * 2, 256, 0, stream>>>(h2g, W3f, bb3o, (float*)d_out, s0);
    }
}